// Round 10
// baseline (356.392 us; speedup 1.0000x reference)
//
#include <hip/hip_runtime.h>
#include <hip/hip_bf16.h>
#include <hip/hip_fp16.h>

#define NNODES 100000
#define NEDGES 1600000
#define NB     64
#define NG     16
#define POOL_SLOTS (NB * NG + NB)   // 1088: [64x16 pooled | 64 counts]

// CSR counting-sort parameters
#define BKT_SHIFT 7
#define NPB 128                               // nodes per bucket
#define NBKT ((NNODES + NPB - 1) / NPB)       // 782
#define BCAP 4096                             // per-bucket capacity (mean ~2046)
#define SCAT_BLOCKS 256
#define NL1_BLOCKS 2048
#define DS_CHUNK 4096                         // deg-sort chunk (nodes per block)

typedef float vf2 __attribute__((ext_vector_type(2)));

__device__ __forceinline__ float leaky02(float v) {
    return v > 0.0f ? v : 0.2f * v;
}
__device__ __forceinline__ float elu1(float v) {
    return v > 0.0f ? v : __expf(v) - 1.0f;
}
__device__ __forceinline__ float dot4(float4 a, float4 b) {
    return a.x * b.x + a.y * b.y + a.z * b.z + a.w * b.w;
}

// ---- fp8 (OCP e4m3, gfx950-native) helpers ----
__device__ __forceinline__ int packQ4(float4 v) {
    int pk = __builtin_amdgcn_cvt_pk_fp8_f32(v.x, v.y, 0, false);
    pk = __builtin_amdgcn_cvt_pk_fp8_f32(v.z, v.w, pk, true);
    return pk;
}
// load 4 consecutive fp8 as float4 (4-byte aligned) — 1 load + 2 pk-cvt
__device__ __forceinline__ float4 loadQ4(const unsigned char* p) {
    int u = *(const int*)p;
    vf2 lo = __builtin_amdgcn_cvt_pk_f32_fp8(u, false);
    vf2 hi = __builtin_amdgcn_cvt_pk_f32_fp8(u, true);
    return make_float4(lo.x, lo.y, hi.x, hi.y);
}

// ---------------------------------------------------------------------------
// fold_prep: one tiny block. FOLD[256]:
//  [0:64)  w1s[h][j] = sum_c W1[j][h*16+c]*a1s[h][c]
//  [64:128) w1d, [128:192) w3s, [192:256) w3d
// ---------------------------------------------------------------------------
__global__ void fold_prep(const float* __restrict__ W1,
                          const float* __restrict__ a1s,
                          const float* __restrict__ a1d,
                          const float* __restrict__ W3,
                          const float* __restrict__ a3s,
                          const float* __restrict__ a3d,
                          float* __restrict__ FOLD) {
    int t = threadIdx.x;              // 256 threads
    int blk = t >> 6, h = (t >> 4) & 3, j = t & 15;
    const float* W = (blk < 2) ? W1 : W3;
    const float* a = (blk == 0) ? a1s : (blk == 1) ? a1d : (blk == 2) ? a3s : a3d;
    float s = 0.f;
    for (int c = 0; c < 16; ++c) s += W[j * 64 + h * 16 + c] * a[h * 16 + c];
    FOLD[t] = s;
}

// ---------------------------------------------------------------------------
// Light layer-1 node prep: quad-per-node. Quantize x -> fp8 [n,16]; AS1/AD1
// via PRECOMPUTED folded vectors.
// ---------------------------------------------------------------------------
__device__ __forceinline__ void nl1_body(const float* __restrict__ X,
                                         const float* __restrict__ FOLD,
                                         unsigned char* __restrict__ Xq,
                                         float* __restrict__ AS,
                                         float* __restrict__ AD, int n,
                                         int quad0, int nquads, int q) {
    float4 ws[4], wd[4];
#pragma unroll
    for (int h = 0; h < 4; ++h) {
        ws[h] = *(const float4*)&FOLD[h * 16 + 4 * q];
        wd[h] = *(const float4*)&FOLD[64 + h * 16 + 4 * q];
    }
    for (int i = quad0; i < n; i += nquads) {
        float4 x4 = *(const float4*)(X + (size_t)i * 16 + 4 * q);
        *(int*)(Xq + (size_t)i * 16 + 4 * q) = packQ4(x4);
        float s[4], d[4];
#pragma unroll
        for (int h = 0; h < 4; ++h) { s[h] = dot4(x4, ws[h]); d[h] = dot4(x4, wd[h]); }
#pragma unroll
        for (int h = 0; h < 4; ++h) {
            s[h] += __shfl_xor(s[h], 1); s[h] += __shfl_xor(s[h], 2);
            d[h] += __shfl_xor(d[h], 1); d[h] += __shfl_xor(d[h], 2);
        }
        if (q == 0) *(float4*)(AS + (size_t)i * 4) = make_float4(s[0], s[1], s[2], s[3]);
        if (q == 1) *(float4*)(AD + (size_t)i * 4) = make_float4(d[0], d[1], d[2], d[3]);
    }
}

// ---------------------------------------------------------------------------
// FUSED: bucket_scatter (blocks [0,SCAT_BLOCKS)) + layer-1 node prep.
// ---------------------------------------------------------------------------
__global__ void scatter_nl1(const int* __restrict__ src,
                            const int* __restrict__ dst,
                            int* __restrict__ bucketCnt,
                            unsigned int* __restrict__ pairs, int ne,
                            const float* __restrict__ X,
                            const float* __restrict__ FOLD,
                            unsigned char* __restrict__ Xq,
                            float* __restrict__ AS,
                            float* __restrict__ AD, int n) {
    __shared__ int hist[NBKT];
    __shared__ int base[NBKT];
    int tid = threadIdx.x;

    if (blockIdx.x >= SCAT_BLOCKS) {
        int q = tid & 3;
        int quad0 = ((blockIdx.x - SCAT_BLOCKS) * 256 + tid) >> 2;
        int nquads = (NL1_BLOCKS * 256) >> 2;
        nl1_body(X, FOLD, Xq, AS, AD, n, quad0, nquads, q);
        return;
    }

    // ---- scatter part ----
    for (int i = tid; i < NBKT; i += 256) hist[i] = 0;
    __syncthreads();

    int chunk = (ne + SCAT_BLOCKS - 1) / SCAT_BLOCKS;
    int beg = blockIdx.x * chunk;
    int end = min(beg + chunk, ne);

    for (int e0 = beg; e0 < end; e0 += 1024) {
        int d[4];
#pragma unroll
        for (int q = 0; q < 4; ++q) {
            int e = e0 + q * 256 + tid;
            d[q] = (e < end) ? dst[e] : -1;
        }
#pragma unroll
        for (int q = 0; q < 4; ++q)
            if (d[q] >= 0) atomicAdd(&hist[d[q] >> BKT_SHIFT], 1);
    }
    __syncthreads();

    for (int i = tid; i < NBKT; i += 256) {
        int h = hist[i];
        base[i] = h ? atomicAdd(&bucketCnt[i], h) : 0;  // reserve range
        hist[i] = 0;                                    // reuse as cursor
    }
    __syncthreads();

    for (int e0 = beg; e0 < end; e0 += 1024) {
        int d[4], s[4];
#pragma unroll
        for (int q = 0; q < 4; ++q) {
            int e = e0 + q * 256 + tid;
            d[q] = (e < end) ? dst[e] : -1;
            s[q] = (e < end) ? src[e] : 0;
        }
        int r[4], bkt[4];
#pragma unroll
        for (int q = 0; q < 4; ++q) {
            if (d[q] >= 0) {
                bkt[q] = d[q] >> BKT_SHIFT;
                r[q] = base[bkt[q]] + atomicAdd(&hist[bkt[q]], 1);
            }
        }
#pragma unroll
        for (int q = 0; q < 4; ++q) {
            if (d[q] >= 0 && r[q] < BCAP)
                pairs[(size_t)bkt[q] * BCAP + r[q]] =
                    (unsigned)s[q] | ((unsigned)(d[q] & (NPB - 1)) << 20);
        }
    }
}

// ---------------------------------------------------------------------------
// bucket_sort with inline offset computation
// ---------------------------------------------------------------------------
__global__ void bucket_sort(const unsigned int* __restrict__ pairs,
                            const int* __restrict__ bucketCnt,
                            int* __restrict__ srcs,
                            int* __restrict__ indptr, int n) {
    __shared__ int hist[NPB];
    __shared__ int offl[NPB];
    __shared__ int cur[NPB];
    __shared__ int red[256];
    __shared__ int lsrc[BCAP];
    int bkt = blockIdx.x;
    int t = threadIdx.x;
    int cnt = min(bucketCnt[bkt], BCAP);

    int partial = 0;
    for (int j = t; j < bkt; j += 256) partial += min(bucketCnt[j], BCAP);
    red[t] = partial;
    if (t < NPB) hist[t] = 0;
    __syncthreads();
    for (int s = 128; s > 0; s >>= 1) {
        if (t < s) red[t] += red[t + s];
        __syncthreads();
    }
    int boff = red[0];
    if (bkt == NBKT - 1 && t == 0) indptr[n] = boff + cnt;

    const unsigned int* __restrict__ p = pairs + (size_t)bkt * BCAP;
    unsigned int v[BCAP / 256];
#pragma unroll
    for (int i = 0; i < BCAP / 256; ++i) {
        int e = i * 256 + t;
        v[i] = 0u;
        if (e < cnt) {
            v[i] = p[e];
            atomicAdd(&hist[v[i] >> 20], 1);
        }
    }
    __syncthreads();
    if (t < NPB) offl[t] = hist[t];
    __syncthreads();
    for (int off = 1; off < NPB; off <<= 1) {
        int x = 0;
        if (t < NPB && t >= off) x = offl[t - off];
        __syncthreads();
        if (t < NPB && t >= off) offl[t] += x;
        __syncthreads();
    }
    if (t < NPB) {
        int ex = offl[t] - hist[t];   // exclusive
        cur[t] = ex;
        int node = bkt * NPB + t;
        if (node < n) indptr[node] = boff + ex;
    }
    __syncthreads();
#pragma unroll
    for (int i = 0; i < BCAP / 256; ++i) {
        int e = i * 256 + t;
        if (e < cnt) {
            int r = atomicAdd(&cur[v[i] >> 20], 1);
            lsrc[r] = (int)(v[i] & 0xFFFFFu);
        }
    }
    __syncthreads();
    for (int e = t; e < cnt; e += 256) srcs[boff + e] = lsrc[e];
}

// ---------------------------------------------------------------------------
// deg_sort: per-4096-node chunk LDS counting-sort of node ids by degree.
// perm[c0..c1) = node ids ordered by degree (asc) within the chunk, so the
// 4 node-groups of a pull wave get near-equal degrees (kills intra-wave
// exec-mask divergence: E[max of 4 iid degrees] ~ 1.3x mean).
// ---------------------------------------------------------------------------
__global__ void deg_sort(const int* __restrict__ indptr,
                         int* __restrict__ perm, int n) {
    __shared__ int hist[64];
    __shared__ int cur[64];
    int t = threadIdx.x;
    int c0 = blockIdx.x * DS_CHUNK;
    int c1 = min(c0 + DS_CHUNK, n);
    if (t < 64) hist[t] = 0;
    __syncthreads();
    for (int i = c0 + t; i < c1; i += 256) {
        int deg = min(indptr[i + 1] - indptr[i], 63);
        atomicAdd(&hist[deg], 1);
    }
    __syncthreads();
    if (t == 0) {
        int acc = 0;
        for (int k = 0; k < 64; ++k) { int h = hist[k]; cur[k] = acc; acc += h; }
    }
    __syncthreads();
    for (int i = c0 + t; i < c1; i += 256) {
        int deg = min(indptr[i + 1] - indptr[i], 63);
        int pos = atomicAdd(&cur[deg], 1);
        perm[c0 + pos] = i;
    }
}

// ---------------------------------------------------------------------------
// Aggregation core, 16B fp8 rows (layers 1 & 3). Gathered set = Xq 1.6MB
// + AS 1.6MB -> L2-resident. ILP-4, lean (verified 321us structure).
// ---------------------------------------------------------------------------
__device__ __forceinline__ float4 gat_agg16(
    const unsigned char* __restrict__ Xq, const float* __restrict__ AS,
    const float* __restrict__ AD,
    const int* __restrict__ indptr, const int* __restrict__ srcs,
    int d, int grp, int sl, int head, int dq, float& denOut) {
    float ad  = AD[(size_t)d * 4 + head];
    float asd = AS[(size_t)d * 4 + head];
    float t0 = asd + ad;                       // self-loop
    float wself = __expf(leaky02(t0));
    float den = wself;
    float4 x4s = loadQ4(Xq + (size_t)d * 16 + dq * 4);
    float4 acc = make_float4(wself * x4s.x, wself * x4s.y,
                             wself * x4s.z, wself * x4s.w);

    int beg = indptr[d], end = indptr[d + 1];
    for (int e0 = beg; e0 < end; e0 += 16) {
        int cnt = min(16, end - e0);
        int myS = (sl < cnt) ? srcs[e0 + sl] : 0;
        int j = 0;
        for (; j + 4 <= cnt; j += 4) {             // 4 gathers in flight
            int s[4]; float a[4]; float4 h4[4];
#pragma unroll
            for (int q = 0; q < 4; ++q)
                s[q] = __shfl(myS, (grp << 4) + j + q);
#pragma unroll
            for (int q = 0; q < 4; ++q)
                a[q] = AS[(size_t)s[q] * 4 + head];
#pragma unroll
            for (int q = 0; q < 4; ++q)
                h4[q] = loadQ4(Xq + (size_t)s[q] * 16 + dq * 4);
#pragma unroll
            for (int q = 0; q < 4; ++q) {
                float t = a[q] + ad;
                float w = __expf(leaky02(t));
                den += w;
                acc.x += w * h4[q].x; acc.y += w * h4[q].y;
                acc.z += w * h4[q].z; acc.w += w * h4[q].w;
            }
        }
        for (; j < cnt; ++j) {                     // tail
            int s = __shfl(myS, (grp << 4) + j);
            float t = AS[(size_t)s * 4 + head] + ad;
            float w = __expf(leaky02(t));
            float4 h4 = loadQ4(Xq + (size_t)s * 16 + dq * 4);
            den += w;
            acc.x += w * h4.x; acc.y += w * h4.y;
            acc.z += w * h4.z; acc.w += w * h4.w;
        }
    }
    denOut = den;
    return acc;
}

// ---------------------------------------------------------------------------
// Aggregation core, 64B fp8 rows (layer 2).
// ---------------------------------------------------------------------------
__device__ __forceinline__ float4 gat_agg64(
    const unsigned char* __restrict__ H, const float* __restrict__ AS,
    const float* __restrict__ AD,
    const int* __restrict__ indptr, const int* __restrict__ srcs,
    int d, int grp, int sl, int head, float& denOut) {
    float ad  = AD[(size_t)d * 4 + head];
    float asd = AS[(size_t)d * 4 + head];
    float t0 = asd + ad;
    float wself = __expf(leaky02(t0));
    float den = wself;
    float4 h4s = loadQ4(H + (size_t)d * 64 + sl * 4);
    float4 acc = make_float4(wself * h4s.x, wself * h4s.y,
                             wself * h4s.z, wself * h4s.w);

    int beg = indptr[d], end = indptr[d + 1];
    for (int e0 = beg; e0 < end; e0 += 16) {
        int cnt = min(16, end - e0);
        int myS = (sl < cnt) ? srcs[e0 + sl] : 0;
        int j = 0;
        for (; j + 4 <= cnt; j += 4) {
            int s[4]; float a[4]; float4 h4[4];
#pragma unroll
            for (int q = 0; q < 4; ++q)
                s[q] = __shfl(myS, (grp << 4) + j + q);
#pragma unroll
            for (int q = 0; q < 4; ++q)
                a[q] = AS[(size_t)s[q] * 4 + head];
#pragma unroll
            for (int q = 0; q < 4; ++q)
                h4[q] = loadQ4(H + (size_t)s[q] * 64 + sl * 4);
#pragma unroll
            for (int q = 0; q < 4; ++q) {
                float t = a[q] + ad;
                float w = __expf(leaky02(t));
                den += w;
                acc.x += w * h4[q].x; acc.y += w * h4[q].y;
                acc.z += w * h4[q].z; acc.w += w * h4[q].w;
            }
        }
        for (; j < cnt; ++j) {
            int s = __shfl(myS, (grp << 4) + j);
            float t = AS[(size_t)s * 4 + head] + ad;
            float w = __expf(leaky02(t));
            float4 h4 = loadQ4(H + (size_t)s * 64 + sl * 4);
            den += w;
            acc.x += w * h4.x; acc.y += w * h4.y;
            acc.z += w * h4.z; acc.w += w * h4.w;
        }
    }
    denOut = den;
    return acc;
}

// ---------------------------------------------------------------------------
// layer 1 + FUSED layer-2 node_linear:
// agg16(x) -> W1 -> +b1,ELU = c1 (in-register) -> W2 -> Hq2 fp8 + AS2/AD2.
// Nodes processed in degree-sorted order via perm (divergence kill).
// ---------------------------------------------------------------------------
__global__ void gat_pull_l1(const unsigned char* __restrict__ Xq,
                            const float* __restrict__ AS,
                            float* __restrict__ AD,
                            const int* __restrict__ indptr,
                            const int* __restrict__ srcs,
                            const int* __restrict__ perm,
                            const float* __restrict__ W1,   // [16][64]
                            const float* __restrict__ b1,   // [64]
                            const float* __restrict__ W2,   // [64][64]
                            const float* __restrict__ a2s,  // [4][16]
                            const float* __restrict__ a2d,  // [4][16]
                            unsigned char* __restrict__ Hq2,
                            float* __restrict__ AS2, int n) {
    __shared__ float w1s[16 * 64];
    __shared__ float w2s[64 * 64];
    for (int i = threadIdx.x; i < 16 * 64; i += 256) w1s[i] = W1[i];
    for (int i = threadIdx.x; i < 64 * 64; i += 256) w2s[i] = W2[i];
    __syncthreads();

    int lane = threadIdx.x & 63;
    int grp = lane >> 4, sl = lane & 15, head = sl >> 2, dq = sl & 3;
    int wave = (blockIdx.x * blockDim.x + threadIdx.x) >> 6;
    int nwaves = (gridDim.x * blockDim.x) >> 6;

    for (int i0 = wave * 4; i0 < n; i0 += nwaves * 4) {
        int idx = i0 + grp;
        if (idx >= n) continue;
        int d = perm[idx];
        float den;
        float4 acc = gat_agg16(Xq, AS, AD, indptr, srcs, d, grp, sl, head, dq, den);
        float inv = 1.0f / (den + 1e-16f);
        float4 v = make_float4(acc.x * inv, acc.y * inv, acc.z * inv, acc.w * inv);

        // ---- W1 transform: c1 channels 4sl..4sl+3 (head = sl>>2) ----
        float4 o = make_float4(0.f, 0.f, 0.f, 0.f);
#pragma unroll
        for (int p = 0; p < 4; ++p) {
            int srcl = (grp << 4) + head * 4 + p;   // agg dims 4p..4p+3, my head
            float4 xq;
            xq.x = __shfl(v.x, srcl); xq.y = __shfl(v.y, srcl);
            xq.z = __shfl(v.z, srcl); xq.w = __shfl(v.w, srcl);
            const float* wr = &w1s[(4 * p) * 64 + 4 * sl];
            float4 w0 = *(const float4*)(wr);
            float4 w1r = *(const float4*)(wr + 64);
            float4 w2r = *(const float4*)(wr + 128);
            float4 w3r = *(const float4*)(wr + 192);
            o.x += xq.x * w0.x + xq.y * w1r.x + xq.z * w2r.x + xq.w * w3r.x;
            o.y += xq.x * w0.y + xq.y * w1r.y + xq.z * w2r.y + xq.w * w3r.y;
            o.z += xq.x * w0.z + xq.y * w1r.z + xq.z * w2r.z + xq.w * w3r.z;
            o.w += xq.x * w0.w + xq.y * w1r.w + xq.z * w2r.w + xq.w * w3r.w;
        }
        float4 bb = *(const float4*)(b1 + 4 * sl);
        o.x = elu1(o.x + bb.x); o.y = elu1(o.y + bb.y);
        o.z = elu1(o.z + bb.z); o.w = elu1(o.w + bb.w);

        // ---- W2 transform: h2 channels 4sl..4sl+3 = sum_k c1[k]*W2[k][.] ----
        float4 h2 = make_float4(0.f, 0.f, 0.f, 0.f);
#pragma unroll 4
        for (int p = 0; p < 16; ++p) {
            int srcl = (grp << 4) + p;              // c1 channels 4p..4p+3
            float c0 = __shfl(o.x, srcl), c1v = __shfl(o.y, srcl);
            float c2v = __shfl(o.z, srcl), c3v = __shfl(o.w, srcl);
            const float* wr = &w2s[(4 * p) * 64 + 4 * sl];
            float4 w0 = *(const float4*)(wr);
            float4 w1r = *(const float4*)(wr + 64);
            float4 w2r = *(const float4*)(wr + 128);
            float4 w3r = *(const float4*)(wr + 192);
            h2.x += c0 * w0.x + c1v * w1r.x + c2v * w2r.x + c3v * w3r.x;
            h2.y += c0 * w0.y + c1v * w1r.y + c2v * w2r.y + c3v * w3r.y;
            h2.z += c0 * w0.z + c1v * w1r.z + c2v * w2r.z + c3v * w3r.z;
            h2.w += c0 * w0.w + c1v * w1r.w + c2v * w2r.w + c3v * w3r.w;
        }
        *(int*)(Hq2 + (size_t)d * 64 + 4 * sl) = packQ4(h2);

        // ---- AS2/AD2 ----
        float4 as4 = *(const float4*)(a2s + head * 16 + 4 * dq);
        float4 ad4 = *(const float4*)(a2d + head * 16 + 4 * dq);
        float s1 = dot4(h2, as4), s2 = dot4(h2, ad4);
        s1 += __shfl_xor(s1, 1); s1 += __shfl_xor(s1, 2);
        s2 += __shfl_xor(s2, 1); s2 += __shfl_xor(s2, 2);
        if (dq == 0) {
            AS2[(size_t)d * 4 + head] = s1;
            AD[(size_t)d * 4 + head] = s2;   // own-dst only; read before write
        }
    }
}

// ---------------------------------------------------------------------------
// layer 2: agg64 -> head-mean + b2 + ELU = c2 -> Xq3 fp8 + AS3/AD3 (folded).
// ---------------------------------------------------------------------------
__global__ void gat_pull_l2(const unsigned char* __restrict__ H,
                            const float* __restrict__ AS,
                            float* __restrict__ AD,
                            const int* __restrict__ indptr,
                            const int* __restrict__ srcs,
                            const int* __restrict__ perm,
                            const float* __restrict__ bias,   // b2 [16]
                            const float* __restrict__ FOLD,   // [256]
                            unsigned char* __restrict__ Xq3,  // [n,16] fp8 out
                            float* __restrict__ AS3, int n) {
    int lane = threadIdx.x & 63;
    int grp = lane >> 4, sl = lane & 15, head = sl >> 2, dq = sl & 3;
    int wave = (blockIdx.x * blockDim.x + threadIdx.x) >> 6;
    int nwaves = (gridDim.x * blockDim.x) >> 6;

    float4 w3s4 = *(const float4*)&FOLD[128 + head * 16 + 4 * dq];
    float4 w3d4 = *(const float4*)&FOLD[192 + head * 16 + 4 * dq];
    float4 b4 = *(const float4*)(bias + dq * 4);

    for (int i0 = wave * 4; i0 < n; i0 += nwaves * 4) {
        int idx = i0 + grp;
        if (idx >= n) continue;
        int d = perm[idx];
        float den;
        float4 acc = gat_agg64(H, AS, AD, indptr, srcs, d, grp, sl, head, den);
        float inv = 1.0f / (den + 1e-16f);
        float4 v = make_float4(acc.x * inv, acc.y * inv, acc.z * inv, acc.w * inv);
        // head-mean fold (lanes sl^4, sl^8 hold other heads, same dq)
#pragma unroll
        for (int off = 4; off <= 8; off <<= 1) {
            v.x += __shfl_xor(v.x, off);
            v.y += __shfl_xor(v.y, off);
            v.z += __shfl_xor(v.z, off);
            v.w += __shfl_xor(v.w, off);
        }
        v.x = elu1(0.25f * v.x + b4.x);
        v.y = elu1(0.25f * v.y + b4.y);
        v.z = elu1(0.25f * v.z + b4.z);
        v.w = elu1(0.25f * v.w + b4.w);
        if (sl < 4)
            *(int*)(Xq3 + (size_t)d * 16 + 4 * sl) = packQ4(v);
        float s1 = dot4(v, w3s4);
        float s2 = dot4(v, w3d4);
        s1 += __shfl_xor(s1, 1); s1 += __shfl_xor(s1, 2);
        s2 += __shfl_xor(s2, 1); s2 += __shfl_xor(s2, 2);
        if (dq == 0) {
            AS3[(size_t)d * 4 + head] = s1;
            AD[(size_t)d * 4 + head] = s2;   // own-dst only; read before write
        }
    }
}

// ---------------------------------------------------------------------------
// layer 3: agg16(c2) -> per-head W3 -> head-mean + b3 -> FUSED mean-pool.
// ---------------------------------------------------------------------------
__global__ void gat_pull_l3(const unsigned char* __restrict__ Xq,
                            const float* __restrict__ AS,
                            const float* __restrict__ AD,
                            const int* __restrict__ indptr,
                            const int* __restrict__ srcs,
                            const int* __restrict__ perm,
                            const float* __restrict__ W3,     // [16][64]
                            const float* __restrict__ bias,   // b3 [16]
                            const int* __restrict__ batch,
                            float* __restrict__ PC, int n) {
    __shared__ float w3lds[16 * 64];
    __shared__ float lp[POOL_SLOTS];
    for (int i = threadIdx.x; i < 16 * 64; i += 256) w3lds[i] = W3[i];
    for (int i = threadIdx.x; i < POOL_SLOTS; i += 256) lp[i] = 0.f;
    __syncthreads();

    int lane = threadIdx.x & 63;
    int grp = lane >> 4, sl = lane & 15, head = sl >> 2, dq = sl & 3;
    int wave = (blockIdx.x * blockDim.x + threadIdx.x) >> 6;
    int nwaves = (gridDim.x * blockDim.x) >> 6;
    float4 b4 = *(const float4*)(bias + dq * 4);

    for (int i0 = wave * 4; i0 < n; i0 += nwaves * 4) {
        int idx = i0 + grp;
        if (idx < n) {
            int d = perm[idx];
            float den;
            float4 acc = gat_agg16(Xq, AS, AD, indptr, srcs, d, grp, sl, head, dq, den);
            float inv = 1.0f / (den + 1e-16f);
            float4 v = make_float4(acc.x * inv, acc.y * inv, acc.z * inv, acc.w * inv);
            // per-head transform: h3[head][within-head ch 4dq..4dq+3]
            float4 o = make_float4(0.f, 0.f, 0.f, 0.f);
#pragma unroll
            for (int p = 0; p < 4; ++p) {
                int srcl = (grp << 4) + head * 4 + p;   // agg dims 4p..4p+3
                float4 xq;
                xq.x = __shfl(v.x, srcl); xq.y = __shfl(v.y, srcl);
                xq.z = __shfl(v.z, srcl); xq.w = __shfl(v.w, srcl);
                const float* wr = &w3lds[(4 * p) * 64 + head * 16 + 4 * dq];
                float4 w0 = *(const float4*)(wr);
                float4 w1r = *(const float4*)(wr + 64);
                float4 w2r = *(const float4*)(wr + 128);
                float4 w3r = *(const float4*)(wr + 192);
                o.x += xq.x * w0.x + xq.y * w1r.x + xq.z * w2r.x + xq.w * w3r.x;
                o.y += xq.x * w0.y + xq.y * w1r.y + xq.z * w2r.y + xq.w * w3r.y;
                o.z += xq.x * w0.z + xq.y * w1r.z + xq.z * w2r.z + xq.w * w3r.z;
                o.w += xq.x * w0.w + xq.y * w1r.w + xq.z * w2r.w + xq.w * w3r.w;
            }
            // head-mean fold
#pragma unroll
            for (int off = 4; off <= 8; off <<= 1) {
                o.x += __shfl_xor(o.x, off);
                o.y += __shfl_xor(o.y, off);
                o.z += __shfl_xor(o.z, off);
                o.w += __shfl_xor(o.w, off);
            }
            o.x = 0.25f * o.x + b4.x; o.y = 0.25f * o.y + b4.y;
            o.z = 0.25f * o.z + b4.z; o.w = 0.25f * o.w + b4.w;
            if (sl < 4) {                 // lanes 0..3 hold quads 0..3
                int b = batch[d];
                atomicAdd(&lp[b * 16 + sl * 4 + 0], o.x);
                atomicAdd(&lp[b * 16 + sl * 4 + 1], o.y);
                atomicAdd(&lp[b * 16 + sl * 4 + 2], o.z);
                atomicAdd(&lp[b * 16 + sl * 4 + 3], o.w);
                if (sl == 0) atomicAdd(&lp[NB * NG + b], 1.0f);
            }
        }
    }
    __syncthreads();
    for (int i = threadIdx.x; i < POOL_SLOTS; i += 256) {
        float s = lp[i];
        if (s != 0.f) atomicAdd(&PC[i], s);
    }
}

// final MLP head, one thread per graph
__global__ void mlp_head(const float* __restrict__ pooled_counts,
                         const float* __restrict__ stats,
                         const float* __restrict__ fw1, const float* __restrict__ fb1,
                         const float* __restrict__ fw2, const float* __restrict__ fb2,
                         const float* __restrict__ fw3, const float* __restrict__ fb3,
                         float* __restrict__ out) {
    int g = threadIdx.x;
    if (g >= NB) return;
    const float* pooled = pooled_counts;
    const float* counts = pooled_counts + NB * NG;
    float z[32];
    float inv = 1.0f / fmaxf(counts[g], 1.0f);
#pragma unroll
    for (int c = 0; c < 16; ++c) z[c] = pooled[g * 16 + c] * inv;
#pragma unroll
    for (int c = 0; c < 16; ++c) z[16 + c] = stats[g * 16 + c];

    float z1[32];
#pragma unroll
    for (int j = 0; j < 32; ++j) {
        float acc = fb1[j];
        for (int k = 0; k < 32; ++k) acc += z[k] * fw1[k * 32 + j];
        z1[j] = fmaxf(acc, 0.0f);
    }
    float z2[16];
#pragma unroll
    for (int j = 0; j < 16; ++j) {
        float acc = fb2[j];
        for (int k = 0; k < 32; ++k) acc += z1[k] * fw2[k * 16 + j];
        z2[j] = fmaxf(acc, 0.0f);
    }
    float acc = fb3[0];
#pragma unroll
    for (int k = 0; k < 16; ++k) acc += z2[k] * fw3[k];
    out[g] = acc;
}

extern "C" void kernel_launch(void* const* d_in, const int* in_sizes, int n_in,
                              void* d_out, int out_size, void* d_ws, size_t ws_size,
                              hipStream_t stream) {
    const float* x    = (const float*)d_in[0];
    const float* stats= (const float*)d_in[1];
    const float* W1   = (const float*)d_in[2];
    const float* a1s  = (const float*)d_in[3];
    const float* a1d  = (const float*)d_in[4];
    const float* b1   = (const float*)d_in[5];
    const float* W2   = (const float*)d_in[6];
    const float* a2s  = (const float*)d_in[7];
    const float* a2d  = (const float*)d_in[8];
    const float* b2   = (const float*)d_in[9];
    const float* W3   = (const float*)d_in[10];
    const float* a3s  = (const float*)d_in[11];
    const float* a3d  = (const float*)d_in[12];
    const float* b3   = (const float*)d_in[13];
    const float* fw1  = (const float*)d_in[14];
    const float* fb1  = (const float*)d_in[15];
    const float* fw2  = (const float*)d_in[16];
    const float* fb2  = (const float*)d_in[17];
    const float* fw3  = (const float*)d_in[18];
    const float* fb3  = (const float*)d_in[19];
    const int* ei     = (const int*)d_in[20];
    const int* batch  = (const int*)d_in[21];

    const int n = NNODES, ne = NEDGES;
    const int* srcI = ei;
    const int* dstI = ei + ne;

    // ---- workspace layout ----
    unsigned char* Xq = (unsigned char*)d_ws;             // [n,16] fp8 (x; later c2)
    unsigned char* Hq2 = Xq + (size_t)n * 16;             // [n,64] fp8 6.4MB
    float* ASa  = (float*)(Hq2 + (size_t)n * 64);         // [n,4] AS1, later AS3
    float* ASb  = ASa + (size_t)n * 4;                    // [n,4] AS2
    float* AD   = ASb + (size_t)n * 4;                    // [n,4] in-place AD
    float* FOLD = AD + (size_t)n * 4;                     // [256]
    float* PC   = FOLD + 256;                             // [1088]
    int* bucketCnt = (int*)(PC + POOL_SLOTS);             // [NBKT]
    int* indptr    = bucketCnt + NBKT;                    // [n+1]
    int* srcs      = indptr + (n + 1);                    // [ne]
    int* perm      = srcs + ne;                           // [n]
    size_t off = (size_t)((char*)(perm + n) - (char*)d_ws);
    off = (off + 255) & ~(size_t)255;
    unsigned int* pairs = (unsigned int*)((char*)d_ws + off); // 12.82MB

    const int TB = 256;
    const int pullBlocks = (n + 15) / 16;   // 4 waves/blk × 4 nodes/wave
    const int dsBlocks = (n + DS_CHUNK - 1) / DS_CHUNK;

    // PC and bucketCnt contiguous: one memset covers both
    hipMemsetAsync(PC, 0, (POOL_SLOTS + NBKT) * sizeof(int), stream);

    // ---- fold attention vectors once (tiny) ----
    fold_prep<<<1, 256, 0, stream>>>(W1, a1s, a1d, W3, a3s, a3d, FOLD);

    // ---- fused: CSR bucket scatter + layer-1 node prep ----
    scatter_nl1<<<SCAT_BLOCKS + NL1_BLOCKS, TB, 0, stream>>>(
        srcI, dstI, bucketCnt, pairs, ne, x, FOLD, Xq, ASa, AD, n);
    bucket_sort<<<NBKT, TB, 0, stream>>>(pairs, bucketCnt, srcs, indptr, n);
    // ---- degree-sorted processing order (kills intra-wave divergence) ----
    deg_sort<<<dsBlocks, TB, 0, stream>>>(indptr, perm, n);

    // ---- layer 1 aggregate + W1 + ELU + FUSED layer-2 linear ----
    gat_pull_l1<<<pullBlocks, TB, 0, stream>>>(Xq, ASa, AD, indptr, srcs, perm,
                                               W1, b1, W2, a2s, a2d,
                                               Hq2, ASb, n);

    // ---- layer 2 aggregate + c2-fp8 + folded AS3/AD3 ----
    gat_pull_l2<<<pullBlocks, TB, 0, stream>>>(Hq2, ASb, AD, indptr, srcs, perm,
                                               b2, FOLD, Xq, ASa, n);

    // ---- layer 3 aggregate + W3 + head-mean + fused pool ----
    gat_pull_l3<<<pullBlocks, TB, 0, stream>>>(Xq, ASa, AD, indptr, srcs, perm,
                                               W3, b3, batch, PC, n);

    // ---- MLP head ----
    mlp_head<<<1, 64, 0, stream>>>(PC, stats, fw1, fb1, fw2, fb2, fw3, fb3,
                                   (float*)d_out);
}

// Round 11
// 315.389 us; speedup vs baseline: 1.1300x; 1.1300x over previous
//
#include <hip/hip_runtime.h>
#include <hip/hip_bf16.h>
#include <hip/hip_fp16.h>

#define NNODES 100000
#define NEDGES 1600000
#define NB     64
#define NG     16
#define POOL_SLOTS (NB * NG + NB)   // 1088: [64x16 pooled | 64 counts]

// CSR counting-sort parameters
#define BKT_SHIFT 7
#define NPB 128                               // nodes per bucket
#define NBKT ((NNODES + NPB - 1) / NPB)       // 782
#define BCAP 4096                             // per-bucket capacity (mean ~2046)
#define SCAT_BLOCKS 256
#define NL1_BLOCKS 2048

typedef float vf2 __attribute__((ext_vector_type(2)));

__device__ __forceinline__ float leaky02(float v) {
    return v > 0.0f ? v : 0.2f * v;
}
__device__ __forceinline__ float elu1(float v) {
    return v > 0.0f ? v : __expf(v) - 1.0f;
}
__device__ __forceinline__ float dot4(float4 a, float4 b) {
    return a.x * b.x + a.y * b.y + a.z * b.z + a.w * b.w;
}

// ---- fp8 (OCP e4m3, gfx950-native) helpers ----
__device__ __forceinline__ int packQ4(float4 v) {
    int pk = __builtin_amdgcn_cvt_pk_fp8_f32(v.x, v.y, 0, false);
    pk = __builtin_amdgcn_cvt_pk_fp8_f32(v.z, v.w, pk, true);
    return pk;
}
// load 4 consecutive fp8 as float4 (4-byte aligned) — 1 load + 2 pk-cvt
__device__ __forceinline__ float4 loadQ4(const unsigned char* p) {
    int u = *(const int*)p;
    vf2 lo = __builtin_amdgcn_cvt_pk_f32_fp8(u, false);
    vf2 hi = __builtin_amdgcn_cvt_pk_f32_fp8(u, true);
    return make_float4(lo.x, lo.y, hi.x, hi.y);
}

// ---------------------------------------------------------------------------
// fold_prep: one tiny block. FOLD[256]:
//  [0:64)  w1s[h][j] = sum_c W1[j][h*16+c]*a1s[h][c]
//  [64:128) w1d, [128:192) w3s, [192:256) w3d
// ---------------------------------------------------------------------------
__global__ void fold_prep(const float* __restrict__ W1,
                          const float* __restrict__ a1s,
                          const float* __restrict__ a1d,
                          const float* __restrict__ W3,
                          const float* __restrict__ a3s,
                          const float* __restrict__ a3d,
                          float* __restrict__ FOLD) {
    int t = threadIdx.x;              // 256 threads
    int blk = t >> 6, h = (t >> 4) & 3, j = t & 15;
    const float* W = (blk < 2) ? W1 : W3;
    const float* a = (blk == 0) ? a1s : (blk == 1) ? a1d : (blk == 2) ? a3s : a3d;
    float s = 0.f;
    for (int c = 0; c < 16; ++c) s += W[j * 64 + h * 16 + c] * a[h * 16 + c];
    FOLD[t] = s;
}

// ---------------------------------------------------------------------------
// Light layer-1 node prep: quad-per-node. Quantize x -> fp8 [n,16]; AS1/AD1
// via PRECOMPUTED folded vectors.
// ---------------------------------------------------------------------------
__device__ __forceinline__ void nl1_body(const float* __restrict__ X,
                                         const float* __restrict__ FOLD,
                                         unsigned char* __restrict__ Xq,
                                         float* __restrict__ AS,
                                         float* __restrict__ AD, int n,
                                         int quad0, int nquads, int q) {
    float4 ws[4], wd[4];
#pragma unroll
    for (int h = 0; h < 4; ++h) {
        ws[h] = *(const float4*)&FOLD[h * 16 + 4 * q];
        wd[h] = *(const float4*)&FOLD[64 + h * 16 + 4 * q];
    }
    for (int i = quad0; i < n; i += nquads) {
        float4 x4 = *(const float4*)(X + (size_t)i * 16 + 4 * q);
        *(int*)(Xq + (size_t)i * 16 + 4 * q) = packQ4(x4);
        float s[4], d[4];
#pragma unroll
        for (int h = 0; h < 4; ++h) { s[h] = dot4(x4, ws[h]); d[h] = dot4(x4, wd[h]); }
#pragma unroll
        for (int h = 0; h < 4; ++h) {
            s[h] += __shfl_xor(s[h], 1); s[h] += __shfl_xor(s[h], 2);
            d[h] += __shfl_xor(d[h], 1); d[h] += __shfl_xor(d[h], 2);
        }
        if (q == 0) *(float4*)(AS + (size_t)i * 4) = make_float4(s[0], s[1], s[2], s[3]);
        if (q == 1) *(float4*)(AD + (size_t)i * 4) = make_float4(d[0], d[1], d[2], d[3]);
    }
}

// ---------------------------------------------------------------------------
// FUSED: bucket_scatter (blocks [0,SCAT_BLOCKS)) + layer-1 node prep.
// ---------------------------------------------------------------------------
__global__ void scatter_nl1(const int* __restrict__ src,
                            const int* __restrict__ dst,
                            int* __restrict__ bucketCnt,
                            unsigned int* __restrict__ pairs, int ne,
                            const float* __restrict__ X,
                            const float* __restrict__ FOLD,
                            unsigned char* __restrict__ Xq,
                            float* __restrict__ AS,
                            float* __restrict__ AD, int n) {
    __shared__ int hist[NBKT];
    __shared__ int base[NBKT];
    int tid = threadIdx.x;

    if (blockIdx.x >= SCAT_BLOCKS) {
        int q = tid & 3;
        int quad0 = ((blockIdx.x - SCAT_BLOCKS) * 256 + tid) >> 2;
        int nquads = (NL1_BLOCKS * 256) >> 2;
        nl1_body(X, FOLD, Xq, AS, AD, n, quad0, nquads, q);
        return;
    }

    // ---- scatter part ----
    for (int i = tid; i < NBKT; i += 256) hist[i] = 0;
    __syncthreads();

    int chunk = (ne + SCAT_BLOCKS - 1) / SCAT_BLOCKS;
    int beg = blockIdx.x * chunk;
    int end = min(beg + chunk, ne);

    for (int e0 = beg; e0 < end; e0 += 1024) {
        int d[4];
#pragma unroll
        for (int q = 0; q < 4; ++q) {
            int e = e0 + q * 256 + tid;
            d[q] = (e < end) ? dst[e] : -1;
        }
#pragma unroll
        for (int q = 0; q < 4; ++q)
            if (d[q] >= 0) atomicAdd(&hist[d[q] >> BKT_SHIFT], 1);
    }
    __syncthreads();

    for (int i = tid; i < NBKT; i += 256) {
        int h = hist[i];
        base[i] = h ? atomicAdd(&bucketCnt[i], h) : 0;  // reserve range
        hist[i] = 0;                                    // reuse as cursor
    }
    __syncthreads();

    for (int e0 = beg; e0 < end; e0 += 1024) {
        int d[4], s[4];
#pragma unroll
        for (int q = 0; q < 4; ++q) {
            int e = e0 + q * 256 + tid;
            d[q] = (e < end) ? dst[e] : -1;
            s[q] = (e < end) ? src[e] : 0;
        }
        int r[4], bkt[4];
#pragma unroll
        for (int q = 0; q < 4; ++q) {
            if (d[q] >= 0) {
                bkt[q] = d[q] >> BKT_SHIFT;
                r[q] = base[bkt[q]] + atomicAdd(&hist[bkt[q]], 1);
            }
        }
#pragma unroll
        for (int q = 0; q < 4; ++q) {
            if (d[q] >= 0 && r[q] < BCAP)
                pairs[(size_t)bkt[q] * BCAP + r[q]] =
                    (unsigned)s[q] | ((unsigned)(d[q] & (NPB - 1)) << 20);
        }
    }
}

// ---------------------------------------------------------------------------
// bucket_sort with inline offset computation
// ---------------------------------------------------------------------------
__global__ void bucket_sort(const unsigned int* __restrict__ pairs,
                            const int* __restrict__ bucketCnt,
                            int* __restrict__ srcs,
                            int* __restrict__ indptr, int n) {
    __shared__ int hist[NPB];
    __shared__ int offl[NPB];
    __shared__ int cur[NPB];
    __shared__ int red[256];
    __shared__ int lsrc[BCAP];
    int bkt = blockIdx.x;
    int t = threadIdx.x;
    int cnt = min(bucketCnt[bkt], BCAP);

    int partial = 0;
    for (int j = t; j < bkt; j += 256) partial += min(bucketCnt[j], BCAP);
    red[t] = partial;
    if (t < NPB) hist[t] = 0;
    __syncthreads();
    for (int s = 128; s > 0; s >>= 1) {
        if (t < s) red[t] += red[t + s];
        __syncthreads();
    }
    int boff = red[0];
    if (bkt == NBKT - 1 && t == 0) indptr[n] = boff + cnt;

    const unsigned int* __restrict__ p = pairs + (size_t)bkt * BCAP;
    unsigned int v[BCAP / 256];
#pragma unroll
    for (int i = 0; i < BCAP / 256; ++i) {
        int e = i * 256 + t;
        v[i] = 0u;
        if (e < cnt) {
            v[i] = p[e];
            atomicAdd(&hist[v[i] >> 20], 1);
        }
    }
    __syncthreads();
    if (t < NPB) offl[t] = hist[t];
    __syncthreads();
    for (int off = 1; off < NPB; off <<= 1) {
        int x = 0;
        if (t < NPB && t >= off) x = offl[t - off];
        __syncthreads();
        if (t < NPB && t >= off) offl[t] += x;
        __syncthreads();
    }
    if (t < NPB) {
        int ex = offl[t] - hist[t];   // exclusive
        cur[t] = ex;
        int node = bkt * NPB + t;
        if (node < n) indptr[node] = boff + ex;
    }
    __syncthreads();
#pragma unroll
    for (int i = 0; i < BCAP / 256; ++i) {
        int e = i * 256 + t;
        if (e < cnt) {
            int r = atomicAdd(&cur[v[i] >> 20], 1);
            lsrc[r] = (int)(v[i] & 0xFFFFFu);
        }
    }
    __syncthreads();
    for (int e = t; e < cnt; e += 256) srcs[boff + e] = lsrc[e];
}

// ---------------------------------------------------------------------------
// Aggregation core, 16B fp8 rows (layers 1 & 3). Gathered set = Xq 1.6MB
// + AS 1.6MB -> L2-resident. ILP-4, lean (verified 321us structure).
// ---------------------------------------------------------------------------
__device__ __forceinline__ float4 gat_agg16(
    const unsigned char* __restrict__ Xq, const float* __restrict__ AS,
    const float* __restrict__ AD,
    const int* __restrict__ indptr, const int* __restrict__ srcs,
    int d, int grp, int sl, int head, int dq, float& denOut) {
    float ad  = AD[(size_t)d * 4 + head];
    float asd = AS[(size_t)d * 4 + head];
    float t0 = asd + ad;                       // self-loop
    float wself = __expf(leaky02(t0));
    float den = wself;
    float4 x4s = loadQ4(Xq + (size_t)d * 16 + dq * 4);
    float4 acc = make_float4(wself * x4s.x, wself * x4s.y,
                             wself * x4s.z, wself * x4s.w);

    int beg = indptr[d], end = indptr[d + 1];
    for (int e0 = beg; e0 < end; e0 += 16) {
        int cnt = min(16, end - e0);
        int myS = (sl < cnt) ? srcs[e0 + sl] : 0;
        int j = 0;
        for (; j + 4 <= cnt; j += 4) {             // 4 gathers in flight
            int s[4]; float a[4]; float4 h4[4];
#pragma unroll
            for (int q = 0; q < 4; ++q)
                s[q] = __shfl(myS, (grp << 4) + j + q);
#pragma unroll
            for (int q = 0; q < 4; ++q)
                a[q] = AS[(size_t)s[q] * 4 + head];
#pragma unroll
            for (int q = 0; q < 4; ++q)
                h4[q] = loadQ4(Xq + (size_t)s[q] * 16 + dq * 4);
#pragma unroll
            for (int q = 0; q < 4; ++q) {
                float t = a[q] + ad;
                float w = __expf(leaky02(t));
                den += w;
                acc.x += w * h4[q].x; acc.y += w * h4[q].y;
                acc.z += w * h4[q].z; acc.w += w * h4[q].w;
            }
        }
        for (; j < cnt; ++j) {                     // tail
            int s = __shfl(myS, (grp << 4) + j);
            float t = AS[(size_t)s * 4 + head] + ad;
            float w = __expf(leaky02(t));
            float4 h4 = loadQ4(Xq + (size_t)s * 16 + dq * 4);
            den += w;
            acc.x += w * h4.x; acc.y += w * h4.y;
            acc.z += w * h4.z; acc.w += w * h4.w;
        }
    }
    denOut = den;
    return acc;
}

// ---------------------------------------------------------------------------
// Aggregation core, 64B fp8 rows (layer 2).
// ---------------------------------------------------------------------------
__device__ __forceinline__ float4 gat_agg64(
    const unsigned char* __restrict__ H, const float* __restrict__ AS,
    const float* __restrict__ AD,
    const int* __restrict__ indptr, const int* __restrict__ srcs,
    int d, int grp, int sl, int head, float& denOut) {
    float ad  = AD[(size_t)d * 4 + head];
    float asd = AS[(size_t)d * 4 + head];
    float t0 = asd + ad;
    float wself = __expf(leaky02(t0));
    float den = wself;
    float4 h4s = loadQ4(H + (size_t)d * 64 + sl * 4);
    float4 acc = make_float4(wself * h4s.x, wself * h4s.y,
                             wself * h4s.z, wself * h4s.w);

    int beg = indptr[d], end = indptr[d + 1];
    for (int e0 = beg; e0 < end; e0 += 16) {
        int cnt = min(16, end - e0);
        int myS = (sl < cnt) ? srcs[e0 + sl] : 0;
        int j = 0;
        for (; j + 4 <= cnt; j += 4) {
            int s[4]; float a[4]; float4 h4[4];
#pragma unroll
            for (int q = 0; q < 4; ++q)
                s[q] = __shfl(myS, (grp << 4) + j + q);
#pragma unroll
            for (int q = 0; q < 4; ++q)
                a[q] = AS[(size_t)s[q] * 4 + head];
#pragma unroll
            for (int q = 0; q < 4; ++q)
                h4[q] = loadQ4(H + (size_t)s[q] * 64 + sl * 4);
#pragma unroll
            for (int q = 0; q < 4; ++q) {
                float t = a[q] + ad;
                float w = __expf(leaky02(t));
                den += w;
                acc.x += w * h4[q].x; acc.y += w * h4[q].y;
                acc.z += w * h4[q].z; acc.w += w * h4[q].w;
            }
        }
        for (; j < cnt; ++j) {
            int s = __shfl(myS, (grp << 4) + j);
            float t = AS[(size_t)s * 4 + head] + ad;
            float w = __expf(leaky02(t));
            float4 h4 = loadQ4(H + (size_t)s * 64 + sl * 4);
            den += w;
            acc.x += w * h4.x; acc.y += w * h4.y;
            acc.z += w * h4.z; acc.w += w * h4.w;
        }
    }
    denOut = den;
    return acc;
}

// ---------------------------------------------------------------------------
// layer 1 + FUSED layer-2 node_linear:
// agg16(x) -> W1 -> +b1,ELU = c1 (in-register) -> W2 -> Hq2 fp8 + AS2/AD2.
// c1 never touches global memory.
// ---------------------------------------------------------------------------
__global__ void gat_pull_l1(const unsigned char* __restrict__ Xq,
                            const float* __restrict__ AS,
                            float* __restrict__ AD,
                            const int* __restrict__ indptr,
                            const int* __restrict__ srcs,
                            const float* __restrict__ W1,   // [16][64]
                            const float* __restrict__ b1,   // [64]
                            const float* __restrict__ W2,   // [64][64]
                            const float* __restrict__ a2s,  // [4][16]
                            const float* __restrict__ a2d,  // [4][16]
                            unsigned char* __restrict__ Hq2,
                            float* __restrict__ AS2, int n) {
    __shared__ float w1s[16 * 64];
    __shared__ float w2s[64 * 64];
    for (int i = threadIdx.x; i < 16 * 64; i += 256) w1s[i] = W1[i];
    for (int i = threadIdx.x; i < 64 * 64; i += 256) w2s[i] = W2[i];
    __syncthreads();

    int lane = threadIdx.x & 63;
    int grp = lane >> 4, sl = lane & 15, head = sl >> 2, dq = sl & 3;
    int wave = (blockIdx.x * blockDim.x + threadIdx.x) >> 6;
    int nwaves = (gridDim.x * blockDim.x) >> 6;

    for (int d0 = wave * 4; d0 < n; d0 += nwaves * 4) {
        int d = d0 + grp;
        if (d >= n) continue;
        float den;
        float4 acc = gat_agg16(Xq, AS, AD, indptr, srcs, d, grp, sl, head, dq, den);
        float inv = 1.0f / (den + 1e-16f);
        float4 v = make_float4(acc.x * inv, acc.y * inv, acc.z * inv, acc.w * inv);

        // ---- W1 transform: c1 channels 4sl..4sl+3 (head = sl>>2) ----
        float4 o = make_float4(0.f, 0.f, 0.f, 0.f);
#pragma unroll
        for (int p = 0; p < 4; ++p) {
            int srcl = (grp << 4) + head * 4 + p;   // agg dims 4p..4p+3, my head
            float4 xq;
            xq.x = __shfl(v.x, srcl); xq.y = __shfl(v.y, srcl);
            xq.z = __shfl(v.z, srcl); xq.w = __shfl(v.w, srcl);
            const float* wr = &w1s[(4 * p) * 64 + 4 * sl];
            float4 w0 = *(const float4*)(wr);
            float4 w1r = *(const float4*)(wr + 64);
            float4 w2r = *(const float4*)(wr + 128);
            float4 w3r = *(const float4*)(wr + 192);
            o.x += xq.x * w0.x + xq.y * w1r.x + xq.z * w2r.x + xq.w * w3r.x;
            o.y += xq.x * w0.y + xq.y * w1r.y + xq.z * w2r.y + xq.w * w3r.y;
            o.z += xq.x * w0.z + xq.y * w1r.z + xq.z * w2r.z + xq.w * w3r.z;
            o.w += xq.x * w0.w + xq.y * w1r.w + xq.z * w2r.w + xq.w * w3r.w;
        }
        float4 bb = *(const float4*)(b1 + 4 * sl);
        o.x = elu1(o.x + bb.x); o.y = elu1(o.y + bb.y);
        o.z = elu1(o.z + bb.z); o.w = elu1(o.w + bb.w);

        // ---- W2 transform: h2 channels 4sl..4sl+3 = sum_k c1[k]*W2[k][.] ----
        float4 h2 = make_float4(0.f, 0.f, 0.f, 0.f);
#pragma unroll 4
        for (int p = 0; p < 16; ++p) {
            int srcl = (grp << 4) + p;              // c1 channels 4p..4p+3
            float c0 = __shfl(o.x, srcl), c1v = __shfl(o.y, srcl);
            float c2v = __shfl(o.z, srcl), c3v = __shfl(o.w, srcl);
            const float* wr = &w2s[(4 * p) * 64 + 4 * sl];
            float4 w0 = *(const float4*)(wr);
            float4 w1r = *(const float4*)(wr + 64);
            float4 w2r = *(const float4*)(wr + 128);
            float4 w3r = *(const float4*)(wr + 192);
            h2.x += c0 * w0.x + c1v * w1r.x + c2v * w2r.x + c3v * w3r.x;
            h2.y += c0 * w0.y + c1v * w1r.y + c2v * w2r.y + c3v * w3r.y;
            h2.z += c0 * w0.z + c1v * w1r.z + c2v * w2r.z + c3v * w3r.z;
            h2.w += c0 * w0.w + c1v * w1r.w + c2v * w2r.w + c3v * w3r.w;
        }
        *(int*)(Hq2 + (size_t)d * 64 + 4 * sl) = packQ4(h2);

        // ---- AS2/AD2 ----
        float4 as4 = *(const float4*)(a2s + head * 16 + 4 * dq);
        float4 ad4 = *(const float4*)(a2d + head * 16 + 4 * dq);
        float s1 = dot4(h2, as4), s2 = dot4(h2, ad4);
        s1 += __shfl_xor(s1, 1); s1 += __shfl_xor(s1, 2);
        s2 += __shfl_xor(s2, 1); s2 += __shfl_xor(s2, 2);
        if (dq == 0) {
            AS2[(size_t)d * 4 + head] = s1;
            AD[(size_t)d * 4 + head] = s2;   // own-dst only; read before write
        }
    }
}

// ---------------------------------------------------------------------------
// layer 2: agg64 -> head-mean + b2 + ELU = c2 -> Xq3 fp8 + AS3/AD3 (folded).
// Lean: no LDS, folded vectors precomputed (2 hot float4 loads).
// ---------------------------------------------------------------------------
__global__ void gat_pull_l2(const unsigned char* __restrict__ H,
                            const float* __restrict__ AS,
                            float* __restrict__ AD,
                            const int* __restrict__ indptr,
                            const int* __restrict__ srcs,
                            const float* __restrict__ bias,   // b2 [16]
                            const float* __restrict__ FOLD,   // [256]
                            unsigned char* __restrict__ Xq3,  // [n,16] fp8 out
                            float* __restrict__ AS3, int n) {
    int lane = threadIdx.x & 63;
    int grp = lane >> 4, sl = lane & 15, head = sl >> 2, dq = sl & 3;
    int wave = (blockIdx.x * blockDim.x + threadIdx.x) >> 6;
    int nwaves = (gridDim.x * blockDim.x) >> 6;

    float4 w3s4 = *(const float4*)&FOLD[128 + head * 16 + 4 * dq];
    float4 w3d4 = *(const float4*)&FOLD[192 + head * 16 + 4 * dq];
    float4 b4 = *(const float4*)(bias + dq * 4);

    for (int d0 = wave * 4; d0 < n; d0 += nwaves * 4) {
        int d = d0 + grp;
        if (d >= n) continue;
        float den;
        float4 acc = gat_agg64(H, AS, AD, indptr, srcs, d, grp, sl, head, den);
        float inv = 1.0f / (den + 1e-16f);
        float4 v = make_float4(acc.x * inv, acc.y * inv, acc.z * inv, acc.w * inv);
        // head-mean fold (lanes sl^4, sl^8 hold other heads, same dq)
#pragma unroll
        for (int off = 4; off <= 8; off <<= 1) {
            v.x += __shfl_xor(v.x, off);
            v.y += __shfl_xor(v.y, off);
            v.z += __shfl_xor(v.z, off);
            v.w += __shfl_xor(v.w, off);
        }
        v.x = elu1(0.25f * v.x + b4.x);
        v.y = elu1(0.25f * v.y + b4.y);
        v.z = elu1(0.25f * v.z + b4.z);
        v.w = elu1(0.25f * v.w + b4.w);
        if (sl < 4)
            *(int*)(Xq3 + (size_t)d * 16 + 4 * sl) = packQ4(v);
        float s1 = dot4(v, w3s4);
        float s2 = dot4(v, w3d4);
        s1 += __shfl_xor(s1, 1); s1 += __shfl_xor(s1, 2);
        s2 += __shfl_xor(s2, 1); s2 += __shfl_xor(s2, 2);
        if (dq == 0) {
            AS3[(size_t)d * 4 + head] = s1;
            AD[(size_t)d * 4 + head] = s2;   // own-dst only; read before write
        }
    }
}

// ---------------------------------------------------------------------------
// layer 3: agg16(c2) -> per-head W3 -> head-mean + b3 -> FUSED mean-pool.
// ---------------------------------------------------------------------------
__global__ void gat_pull_l3(const unsigned char* __restrict__ Xq,
                            const float* __restrict__ AS,
                            const float* __restrict__ AD,
                            const int* __restrict__ indptr,
                            const int* __restrict__ srcs,
                            const float* __restrict__ W3,     // [16][64]
                            const float* __restrict__ bias,   // b3 [16]
                            const int* __restrict__ batch,
                            float* __restrict__ PC, int n) {
    __shared__ float w3lds[16 * 64];
    __shared__ float lp[POOL_SLOTS];
    for (int i = threadIdx.x; i < 16 * 64; i += 256) w3lds[i] = W3[i];
    for (int i = threadIdx.x; i < POOL_SLOTS; i += 256) lp[i] = 0.f;
    __syncthreads();

    int lane = threadIdx.x & 63;
    int grp = lane >> 4, sl = lane & 15, head = sl >> 2, dq = sl & 3;
    int wave = (blockIdx.x * blockDim.x + threadIdx.x) >> 6;
    int nwaves = (gridDim.x * blockDim.x) >> 6;
    float4 b4 = *(const float4*)(bias + dq * 4);

    for (int d0 = wave * 4; d0 < n; d0 += nwaves * 4) {
        int d = d0 + grp;
        if (d < n) {
            float den;
            float4 acc = gat_agg16(Xq, AS, AD, indptr, srcs, d, grp, sl, head, dq, den);
            float inv = 1.0f / (den + 1e-16f);
            float4 v = make_float4(acc.x * inv, acc.y * inv, acc.z * inv, acc.w * inv);
            // per-head transform: h3[head][within-head ch 4dq..4dq+3]
            float4 o = make_float4(0.f, 0.f, 0.f, 0.f);
#pragma unroll
            for (int p = 0; p < 4; ++p) {
                int srcl = (grp << 4) + head * 4 + p;   // agg dims 4p..4p+3
                float4 xq;
                xq.x = __shfl(v.x, srcl); xq.y = __shfl(v.y, srcl);
                xq.z = __shfl(v.z, srcl); xq.w = __shfl(v.w, srcl);
                const float* wr = &w3lds[(4 * p) * 64 + head * 16 + 4 * dq];
                float4 w0 = *(const float4*)(wr);
                float4 w1r = *(const float4*)(wr + 64);
                float4 w2r = *(const float4*)(wr + 128);
                float4 w3r = *(const float4*)(wr + 192);
                o.x += xq.x * w0.x + xq.y * w1r.x + xq.z * w2r.x + xq.w * w3r.x;
                o.y += xq.x * w0.y + xq.y * w1r.y + xq.z * w2r.y + xq.w * w3r.y;
                o.z += xq.x * w0.z + xq.y * w1r.z + xq.z * w2r.z + xq.w * w3r.z;
                o.w += xq.x * w0.w + xq.y * w1r.w + xq.z * w2r.w + xq.w * w3r.w;
            }
            // head-mean fold
#pragma unroll
            for (int off = 4; off <= 8; off <<= 1) {
                o.x += __shfl_xor(o.x, off);
                o.y += __shfl_xor(o.y, off);
                o.z += __shfl_xor(o.z, off);
                o.w += __shfl_xor(o.w, off);
            }
            o.x = 0.25f * o.x + b4.x; o.y = 0.25f * o.y + b4.y;
            o.z = 0.25f * o.z + b4.z; o.w = 0.25f * o.w + b4.w;
            if (sl < 4) {                 // lanes 0..3 hold quads 0..3
                int b = batch[d];
                atomicAdd(&lp[b * 16 + sl * 4 + 0], o.x);
                atomicAdd(&lp[b * 16 + sl * 4 + 1], o.y);
                atomicAdd(&lp[b * 16 + sl * 4 + 2], o.z);
                atomicAdd(&lp[b * 16 + sl * 4 + 3], o.w);
                if (sl == 0) atomicAdd(&lp[NB * NG + b], 1.0f);
            }
        }
    }
    __syncthreads();
    for (int i = threadIdx.x; i < POOL_SLOTS; i += 256) {
        float s = lp[i];
        if (s != 0.f) atomicAdd(&PC[i], s);
    }
}

// final MLP head, one thread per graph
__global__ void mlp_head(const float* __restrict__ pooled_counts,
                         const float* __restrict__ stats,
                         const float* __restrict__ fw1, const float* __restrict__ fb1,
                         const float* __restrict__ fw2, const float* __restrict__ fb2,
                         const float* __restrict__ fw3, const float* __restrict__ fb3,
                         float* __restrict__ out) {
    int g = threadIdx.x;
    if (g >= NB) return;
    const float* pooled = pooled_counts;
    const float* counts = pooled_counts + NB * NG;
    float z[32];
    float inv = 1.0f / fmaxf(counts[g], 1.0f);
#pragma unroll
    for (int c = 0; c < 16; ++c) z[c] = pooled[g * 16 + c] * inv;
#pragma unroll
    for (int c = 0; c < 16; ++c) z[16 + c] = stats[g * 16 + c];

    float z1[32];
#pragma unroll
    for (int j = 0; j < 32; ++j) {
        float acc = fb1[j];
        for (int k = 0; k < 32; ++k) acc += z[k] * fw1[k * 32 + j];
        z1[j] = fmaxf(acc, 0.0f);
    }
    float z2[16];
#pragma unroll
    for (int j = 0; j < 16; ++j) {
        float acc = fb2[j];
        for (int k = 0; k < 32; ++k) acc += z1[k] * fw2[k * 16 + j];
        z2[j] = fmaxf(acc, 0.0f);
    }
    float acc = fb3[0];
#pragma unroll
    for (int k = 0; k < 16; ++k) acc += z2[k] * fw3[k];
    out[g] = acc;
}

extern "C" void kernel_launch(void* const* d_in, const int* in_sizes, int n_in,
                              void* d_out, int out_size, void* d_ws, size_t ws_size,
                              hipStream_t stream) {
    const float* x    = (const float*)d_in[0];
    const float* stats= (const float*)d_in[1];
    const float* W1   = (const float*)d_in[2];
    const float* a1s  = (const float*)d_in[3];
    const float* a1d  = (const float*)d_in[4];
    const float* b1   = (const float*)d_in[5];
    const float* W2   = (const float*)d_in[6];
    const float* a2s  = (const float*)d_in[7];
    const float* a2d  = (const float*)d_in[8];
    const float* b2   = (const float*)d_in[9];
    const float* W3   = (const float*)d_in[10];
    const float* a3s  = (const float*)d_in[11];
    const float* a3d  = (const float*)d_in[12];
    const float* b3   = (const float*)d_in[13];
    const float* fw1  = (const float*)d_in[14];
    const float* fb1  = (const float*)d_in[15];
    const float* fw2  = (const float*)d_in[16];
    const float* fb2  = (const float*)d_in[17];
    const float* fw3  = (const float*)d_in[18];
    const float* fb3  = (const float*)d_in[19];
    const int* ei     = (const int*)d_in[20];
    const int* batch  = (const int*)d_in[21];

    const int n = NNODES, ne = NEDGES;
    const int* srcI = ei;
    const int* dstI = ei + ne;

    // ---- workspace layout ----
    unsigned char* Xq = (unsigned char*)d_ws;             // [n,16] fp8 (x; later c2)
    unsigned char* Hq2 = Xq + (size_t)n * 16;             // [n,64] fp8 6.4MB
    float* ASa  = (float*)(Hq2 + (size_t)n * 64);         // [n,4] AS1, later AS3
    float* ASb  = ASa + (size_t)n * 4;                    // [n,4] AS2
    float* AD   = ASb + (size_t)n * 4;                    // [n,4] in-place AD
    float* FOLD = AD + (size_t)n * 4;                     // [256]
    float* PC   = FOLD + 256;                             // [1088]
    int* bucketCnt = (int*)(PC + POOL_SLOTS);             // [NBKT]
    int* indptr    = bucketCnt + NBKT;                    // [n+1]
    int* srcs      = indptr + (n + 1);                    // [ne]
    size_t off = (size_t)((char*)(srcs + ne) - (char*)d_ws);
    off = (off + 255) & ~(size_t)255;
    unsigned int* pairs = (unsigned int*)((char*)d_ws + off); // 12.82MB

    const int TB = 256;
    const int pullBlocks = (n + 15) / 16;   // 4 waves/blk × 4 nodes/wave

    // PC and bucketCnt contiguous: one memset covers both
    hipMemsetAsync(PC, 0, (POOL_SLOTS + NBKT) * sizeof(int), stream);

    // ---- fold attention vectors once (tiny) ----
    fold_prep<<<1, 256, 0, stream>>>(W1, a1s, a1d, W3, a3s, a3d, FOLD);

    // ---- fused: CSR bucket scatter + layer-1 node prep ----
    scatter_nl1<<<SCAT_BLOCKS + NL1_BLOCKS, TB, 0, stream>>>(
        srcI, dstI, bucketCnt, pairs, ne, x, FOLD, Xq, ASa, AD, n);
    bucket_sort<<<NBKT, TB, 0, stream>>>(pairs, bucketCnt, srcs, indptr, n);

    // ---- layer 1 aggregate + W1 + ELU + FUSED layer-2 linear ----
    gat_pull_l1<<<pullBlocks, TB, 0, stream>>>(Xq, ASa, AD, indptr, srcs,
                                               W1, b1, W2, a2s, a2d,
                                               Hq2, ASb, n);

    // ---- layer 2 aggregate + c2-fp8 + folded AS3/AD3 ----
    gat_pull_l2<<<pullBlocks, TB, 0, stream>>>(Hq2, ASb, AD, indptr, srcs, b2,
                                               FOLD, Xq, ASa, n);

    // ---- layer 3 aggregate + W3 + head-mean + fused pool ----
    gat_pull_l3<<<pullBlocks, TB, 0, stream>>>(Xq, ASa, AD, indptr, srcs,
                                               W3, b3, batch, PC, n);

    // ---- MLP head ----
    mlp_head<<<1, 64, 0, stream>>>(PC, stats, fw1, fb1, fw2, fb2, fw3, fb3,
                                   (float*)d_out);
}